// Round 17
// baseline (124.361 us; speedup 1.0000x reference)
//
#include <hip/hip_runtime.h>
#include <hip/hip_bf16.h>
#include <math.h>

#define B_  8
#define C_  64
#define O_  64
#define H_  128
#define W_  128
#define HW_ (H_ * W_)

typedef __attribute__((ext_vector_type(8))) short bf16x8;
typedef __attribute__((ext_vector_type(4))) float f32x4;

__device__ __forceinline__ short f2bf(float f) {
    __hip_bfloat16 h = __float2bfloat16(f);
    return *reinterpret_cast<short*>(&h);
}
__device__ __forceinline__ float bf2f(short u) {
    unsigned int v = ((unsigned int)(unsigned short)u) << 16;
    return __uint_as_float(v);
}

// ---------------------------------------------------------------------------
// Prep 1: bf16 weights, 16x16 MFMA-A layout [step][mf][l15][g][8].
//   wb2 [18][4][16][4][8]  (deform)          36864 sh
//   wz2 [18][2][16][4][8]  (offset conv)     18432 sh
//   wx2 [18][1][16][4][8]  (mask conv)        9216 sh
// ---------------------------------------------------------------------------
__global__ void prep_weights(const float* __restrict__ w_off,
                             const float* __restrict__ w_mod,
                             const float* __restrict__ w_reg,
                             short* __restrict__ wb2,
                             short* __restrict__ wz2,
                             short* __restrict__ wx2) {
    int t = blockIdx.x * blockDim.x + threadIdx.x;
    if (t < 36864) {
        int step = t / 2048, r = t % 2048;
        int mf = r / 512, r2 = r % 512;
        int l = r2 / 32, r3 = r2 % 32;
        int gg = r3 / 8, j = r3 % 8;
        int kt = step >> 1, ch = step & 1;
        int o = mf * 16 + l, c = ch * 32 + gg * 8 + j;
        wb2[t] = f2bf(w_reg[(o * 64 + c) * 9 + kt]);
    }
    if (t < 18432) {
        int step = t / 1024, r = t % 1024;
        int mf = r / 512, r2 = r % 512;
        int l = r2 / 32, r3 = r2 % 32;
        int gg = r3 / 8, j = r3 % 8;
        int kt = step >> 1, ch = step & 1;
        int m = mf * 16 + l, c = ch * 32 + gg * 8 + j;
        wz2[t] = (m < 18) ? f2bf(w_off[(m * 64 + c) * 9 + kt]) : (short)0;
    }
    if (t < 9216) {
        int step = t / 512, r = t % 512;
        int l = r / 32, r3 = r % 32;
        int gg = r3 / 8, j = r3 % 8;
        int kt = step >> 1, ch = step & 1;
        int c = ch * 32 + gg * 8 + j;
        wx2[t] = (l < 9) ? f2bf(w_mod[(l * 64 + c) * 9 + kt]) : (short)0;
    }
}

// ---------------------------------------------------------------------------
// Prep 2: NCHW fp32 -> NHWC bf16 for x and z.
// ---------------------------------------------------------------------------
__global__ __launch_bounds__(256) void to_nhwc(
    const float* __restrict__ x, const float* __restrict__ z,
    unsigned short* __restrict__ xn, unsigned short* __restrict__ zn) {
    __shared__ float t[64 * 65];
    const int bid = blockIdx.x;
    const int xseg = bid & 1;
    const int y = (bid >> 1) & 127;
    const int b = bid >> 8;

#pragma unroll
    for (int arr = 0; arr < 2; ++arr) {
        const float* src = arr ? z : x;
        unsigned short* dst = arr ? zn : xn;
#pragma unroll
        for (int i = 0; i < 16; ++i) {
            int e = threadIdx.x + i * 256;
            int c = e >> 6, px = e & 63;
            t[px * 65 + c] =
                src[((size_t)(b * 64 + c) * H_ + y) * W_ + xseg * 64 + px];
        }
        __syncthreads();
#pragma unroll
        for (int i = 0; i < 2; ++i) {
            int j = threadIdx.x + i * 256;
            int px = j >> 3, q = j & 7;
            bf16x8 v;
#pragma unroll
            for (int jj = 0; jj < 8; ++jj)
                v[jj] = f2bf(t[px * 65 + q * 8 + jj]);
            *(bf16x8*)(dst +
                       ((size_t)((b * H_ + y) * W_ + xseg * 64 + px)) * 64 +
                       q * 8) = v;
        }
        __syncthreads();
    }
}

// bilinear tap params; also returns UNCLAMPED y0,x0 for the window check
__device__ __forceinline__ void tap_params2(
    int t, int hop, int pxi, float dy, float dx, float m,
    float& w00, float& w01, float& w10, float& w11,
    int& a00, int& a01, int& a10, int& a11, int& y0u, int& x0u) {
    int ky = t / 3, kx = t - 3 * ky;
    float py = dy + (float)(ky + hop - 1);
    float pxf = dx + (float)(kx + pxi - 1);
    float y0f = floorf(py), x0f = floorf(pxf);
    float wy1 = py - y0f, wy0 = 1.f - wy1;
    float wx1 = pxf - x0f, wx0w = 1.f - wx1;
    int y0 = (int)y0f, x0i = (int)x0f;
    int y1 = y0 + 1, x1 = x0i + 1;
    bool vy0 = (y0 >= 0) && (y0 < H_), vy1 = (y1 >= 0) && (y1 < H_);
    bool vx0 = (x0i >= 0) && (x0i < W_), vx1 = (x1 >= 0) && (x1 < W_);
    w00 = wy0 * wx0w * ((vy0 && vx0) ? m : 0.f);
    w01 = wy0 * wx1 * ((vy0 && vx1) ? m : 0.f);
    w10 = wy1 * wx0w * ((vy1 && vx0) ? m : 0.f);
    w11 = wy1 * wx1 * ((vy1 && vx1) ? m : 0.f);
    int y0c = min(max(y0, 0), H_ - 1), y1c = min(max(y1, 0), H_ - 1);
    int x0c = min(max(x0i, 0), W_ - 1), x1c = min(max(x1, 0), W_ - 1);
    a00 = (y0c * W_ + x0c) * 64;
    a01 = (y0c * W_ + x1c) * 64;
    a10 = (y1c * W_ + x0c) * 64;
    a11 = (y1c * W_ + x1c) * 64;
    y0u = y0;
    x0u = x0i;
}

// ---------------------------------------------------------------------------
// FUSED conv + deform (R16 structure). Block = 128 px = 2 rows x 64 cols,
// 8 waves x 16 px; x window 6x69, PSTR=144B, 59.6KB LDS, 2 blocks/CU.
// R17: tap loops unrolled x3 so ~3 taps' weight loads (18-24 independent
// VMEM ops) are in flight together — the weight-load latency (L1-miss,
// ~200-300cy each, 180 loads/wave) is the dominant stall now that corners
// come from LDS. VGPR capped at 128 by __launch_bounds__(512,4).
// ---------------------------------------------------------------------------
#define WROW 6
#define WCOL 69
#define PSTR 72  // shorts per pixel (144B): 64 data + 8 pad -> bank-spread

__global__ __launch_bounds__(512, 4) void dcn_fused(
    const unsigned short* __restrict__ zn, const unsigned short* __restrict__ xn,
    const short* __restrict__ wb2, const short* __restrict__ wz2,
    const short* __restrict__ wx2,
    const float* __restrict__ b_off, const float* __restrict__ b_mod,
    float* __restrict__ out)
{
    __shared__ __align__(16) short sx[WROW * WCOL * PSTR];  // 59616 B

    const int tid = threadIdx.x;
    const int lane = tid & 63;
    const int wv = tid >> 6;        // 0..7
    const int l15 = lane & 15;
    const int g = lane >> 4;
    const int g8 = g * 8;

    // XCD swizzle: 1024 blocks = 8 XCDs x 128; one image per XCD L2.
    int bid = (int)blockIdx.x;
    bid = (bid & 7) * 128 + (bid >> 3);

    // 2 rows x 64 cols tile decomposition
    const int b = bid >> 7;               // 128 blocks per image
    const int rem = bid & 127;
    const int hoB = (rem >> 1) << 1;      // 0,2,..,126
    const int wxB = (rem & 1) << 6;       // 0 or 64

    const int pxi = wv * 16 + l15;        // block-relative pixel 0..127
    const int rowr = pxi >> 6;            // 0 or 1
    const int col = pxi & 63;             // 0..63
    const int hop = hoB + rowr;           // this pixel's row
    const int colg = wxB + col;           // this pixel's global column

    const unsigned short* znb = zn + (size_t)b * HW_ * 64;
    const unsigned short* xnb = xn + (size_t)b * HW_ * 64;

    // ---- stage x window: rows hoB-2..hoB+3, cols wxB-2..wxB+66 (clamped) --
    for (int t = tid; t < WROW * WCOL * 8; t += 512) {
        int pix = t >> 3, q = t & 7;
        int r = pix / WCOL, c = pix - r * WCOL;
        int gy = min(max(hoB - 2 + r, 0), H_ - 1);
        int gx = min(max(wxB - 2 + c, 0), W_ - 1);
        bf16x8 v = *(const bf16x8*)(xnb + (gy * W_ + gx) * 64 + q * 8);
        *(bf16x8*)(sx + pix * PSTR + q * 8) = v;
    }
    __syncthreads();

    // ================= Phase A: offset/mask convs =================
    f32x4 A0 = {0.f, 0.f, 0.f, 0.f}, A1 = A0, A2 = A0;
    const bf16x8 vzero = {0, 0, 0, 0, 0, 0, 0, 0};

#pragma unroll 3
    for (int kt = 0; kt < 9; ++kt) {
        const int ky = kt / 3, kx = kt - 3 * ky;
        const int iy = hop + ky - 1;
        const int ixg = colg + kx - 1;
        const bool v = (iy >= 0) && (iy < H_) && (ixg >= 0) && (ixg < W_);
        const int basez =
            (min(max(iy, 0), H_ - 1) * W_ + min(max(ixg, 0), W_ - 1)) * 64;
        const short* xs =
            sx + ((rowr + ky + 1) * WCOL + col + kx + 1) * PSTR;
#pragma unroll
        for (int ch = 0; ch < 2; ++ch) {
            const int step = kt * 2 + ch;
            bf16x8 bz = *(const bf16x8*)(znb + basez + ch * 32 + g8);
            bf16x8 bx = *(const bf16x8*)(xs + (ch * 4 + g) * 8);
            bf16x8 az0 = *(const bf16x8*)(
                wz2 + (size_t)((step * 2 + 0) * 16 + l15) * 32 + g8);
            bf16x8 az1 = *(const bf16x8*)(
                wz2 + (size_t)((step * 2 + 1) * 16 + l15) * 32 + g8);
            bf16x8 ax = *(const bf16x8*)(
                wx2 + (size_t)(step * 16 + l15) * 32 + g8);
            bz = v ? bz : vzero;
            bx = v ? bx : vzero;
            A0 = __builtin_amdgcn_mfma_f32_16x16x32_bf16(az0, bz, A0, 0, 0, 0);
            A1 = __builtin_amdgcn_mfma_f32_16x16x32_bf16(az1, bz, A1, 0, 0, 0);
            A2 = __builtin_amdgcn_mfma_f32_16x16x32_bf16(ax, bx, A2, 0, 0, 0);
        }
    }

    // ================= Bridge: bias + sigmoid =================
#pragma unroll
    for (int r = 0; r < 4; ++r) A0[r] += b_off[g * 4 + r];
    if (g == 0) {
        A1[0] += b_off[16];
        A1[1] += b_off[17];
    }
    float mk0, mk1, mk2, mk3;
    {
        int j0 = g * 4;
        mk0 = 2.f / (1.f + expf(-(A2[0] + b_mod[min(j0 + 0, 8)])));
        mk1 = 2.f / (1.f + expf(-(A2[1] + b_mod[min(j0 + 1, 8)])));
        mk2 = 2.f / (1.f + expf(-(A2[2] + b_mod[min(j0 + 2, 8)])));
        mk3 = 2.f / (1.f + expf(-(A2[3] + b_mod[min(j0 + 3, 8)])));
    }
    auto get_off = [&](int t, float& dy, float& dx, float& m) {
        if (t < 8) {
            float sdy = (t & 1) ? A0[2] : A0[0];
            float sdx = (t & 1) ? A0[3] : A0[1];
            int ln = (t >> 1) * 16 + l15;
            dy = __shfl(sdy, ln, 64);
            dx = __shfl(sdx, ln, 64);
        } else {
            dy = __shfl(A1[0], l15, 64);
            dx = __shfl(A1[1], l15, 64);
        }
        int tb = t & 3;
        float sm = (tb == 0) ? mk0 : (tb == 1) ? mk1 : (tb == 2) ? mk2 : mk3;
        m = __shfl(sm, (t >> 2) * 16 + l15, 64);
    };

    // ================= Phase B: deformable conv =================
    f32x4 D0 = {0.f, 0.f, 0.f, 0.f}, D1 = D0, D2 = D0, D3 = D0;

#pragma unroll 3
    for (int kt = 0; kt < 9; ++kt) {
        float dy, dx, m;
        get_off(kt, dy, dx, m);
        float w00, w01, w10, w11;
        int a00, a01, a10, a11, y0u, x0u;
        tap_params2(kt, hop, colg, dy, dx, m, w00, w01, w10, w11, a00,
                    a01, a10, a11, y0u, x0u);

        const bool inw = (y0u >= hoB - 2) && (y0u + 1 <= hoB + 3) &&
                         (x0u >= wxB - 2) && (x0u + 1 <= wxB + 66);
        bf16x8 c0l, c1l, c2l, c3l, c0h, c1h, c2h, c3h;
        if (__all(inw)) {
            const int pix00 = (y0u - (hoB - 2)) * WCOL + (x0u - (wxB - 2));
            const short* p00 = sx + pix00 * PSTR;
            const short* p01 = p00 + PSTR;
            const short* p10 = p00 + WCOL * PSTR;
            const short* p11 = p10 + PSTR;
            c0l = *(const bf16x8*)(p00 + g8);
            c1l = *(const bf16x8*)(p01 + g8);
            c2l = *(const bf16x8*)(p10 + g8);
            c3l = *(const bf16x8*)(p11 + g8);
            c0h = *(const bf16x8*)(p00 + 32 + g8);
            c1h = *(const bf16x8*)(p01 + 32 + g8);
            c2h = *(const bf16x8*)(p10 + 32 + g8);
            c3h = *(const bf16x8*)(p11 + 32 + g8);
        } else {
            c0l = *(const bf16x8*)(xnb + a00 + g8);
            c1l = *(const bf16x8*)(xnb + a01 + g8);
            c2l = *(const bf16x8*)(xnb + a10 + g8);
            c3l = *(const bf16x8*)(xnb + a11 + g8);
            c0h = *(const bf16x8*)(xnb + a00 + 32 + g8);
            c1h = *(const bf16x8*)(xnb + a01 + 32 + g8);
            c2h = *(const bf16x8*)(xnb + a10 + 32 + g8);
            c3h = *(const bf16x8*)(xnb + a11 + 32 + g8);
        }

#pragma unroll
        for (int ch = 0; ch < 2; ++ch) {
            const int step = kt * 2 + ch;
            bf16x8 s0 = ch ? c0h : c0l;
            bf16x8 s1 = ch ? c1h : c1l;
            bf16x8 s2 = ch ? c2h : c2l;
            bf16x8 s3 = ch ? c3h : c3l;
            bf16x8 sv;
#pragma unroll
            for (int j = 0; j < 8; ++j) {
                float s = fmaf(bf2f(s0[j]), w00,
                          fmaf(bf2f(s1[j]), w01,
                          fmaf(bf2f(s2[j]), w10, bf2f(s3[j]) * w11)));
                sv[j] = f2bf(s);
            }
            bf16x8 a0 = *(const bf16x8*)(
                wb2 + (size_t)((step * 4 + 0) * 16 + l15) * 32 + g8);
            bf16x8 a1 = *(const bf16x8*)(
                wb2 + (size_t)((step * 4 + 1) * 16 + l15) * 32 + g8);
            bf16x8 a2 = *(const bf16x8*)(
                wb2 + (size_t)((step * 4 + 2) * 16 + l15) * 32 + g8);
            bf16x8 a3 = *(const bf16x8*)(
                wb2 + (size_t)((step * 4 + 3) * 16 + l15) * 32 + g8);
            D0 = __builtin_amdgcn_mfma_f32_16x16x32_bf16(a0, sv, D0, 0, 0, 0);
            D1 = __builtin_amdgcn_mfma_f32_16x16x32_bf16(a1, sv, D1, 0, 0, 0);
            D2 = __builtin_amdgcn_mfma_f32_16x16x32_bf16(a2, sv, D2, 0, 0, 0);
            D3 = __builtin_amdgcn_mfma_f32_16x16x32_bf16(a3, sv, D3, 0, 0, 0);
        }
    }

    // epilogue: o = mf*16 + g*4 + r, pixel = (hop, colg)
    const int pixo = hop * W_ + colg;
#pragma unroll
    for (int mf = 0; mf < 4; ++mf) {
        f32x4 cc = (mf == 0) ? D0 : ((mf == 1) ? D1 : ((mf == 2) ? D2 : D3));
#pragma unroll
        for (int r = 0; r < 4; ++r) {
            const int o = mf * 16 + g * 4 + r;
            out[((size_t)b * O_ + o) * HW_ + pixo] = cc[r];
        }
    }
}

// ---------------------------------------------------------------------------
// Fallback (no workspace): fully fused fp32, slow but correct.
// ---------------------------------------------------------------------------
__global__ __launch_bounds__(256) void deform_fallback(
    const float* __restrict__ x, const float* __restrict__ z,
    const float* __restrict__ w_regp,
    const float* __restrict__ w_off, const float* __restrict__ b_off,
    const float* __restrict__ w_mod, const float* __restrict__ b_mod,
    float* __restrict__ out) {
    int p = blockIdx.x * blockDim.x + threadIdx.x;
    if (p >= B_ * HW_) return;
    int wo = p % W_;
    int ho = (p / W_) % H_;
    int b  = p / HW_;
    int pix = ho * W_ + wo;

    const float* xb = x + (size_t)b * C_ * HW_;

    float accO[18], accM[9];
#pragma unroll
    for (int j = 0; j < 18; ++j) accO[j] = b_off[j];
#pragma unroll
    for (int j = 0; j < 9; ++j) accM[j] = b_mod[j];
    const float* zb = z + (size_t)b * C_ * HW_;
#pragma unroll 1
    for (int c = 0; c < C_; ++c) {
        const float* zc = zb + c * HW_;
        const float* xc = xb + c * HW_;
#pragma unroll
        for (int ky = 0; ky < 3; ++ky) {
            int iy = ho + ky - 1;
            bool vy = (iy >= 0) && (iy < H_);
#pragma unroll
            for (int kx = 0; kx < 3; ++kx) {
                int ix = wo + kx - 1;
                bool v = vy && (ix >= 0) && (ix < W_);
                int k = ky * 3 + kx;
                float zv = v ? zc[iy * W_ + ix] : 0.f;
                float xv = v ? xc[iy * W_ + ix] : 0.f;
#pragma unroll
                for (int j = 0; j < 18; ++j)
                    accO[j] = fmaf(zv, w_off[j * 576 + c * 9 + k], accO[j]);
#pragma unroll
                for (int j = 0; j < 9; ++j)
                    accM[j] = fmaf(xv, w_mod[j * 576 + c * 9 + k], accM[j]);
            }
        }
    }
    float mv[9];
#pragma unroll
    for (int j = 0; j < 9; ++j) mv[j] = 2.f / (1.f + expf(-accM[j]));

    float acc[64];
#pragma unroll
    for (int o = 0; o < 64; ++o) acc[o] = 0.f;

#pragma unroll 1
    for (int k = 0; k < 9; ++k) {
        float dy = accO[2 * k], dx = accO[2 * k + 1], m = mv[k];
        float py = dy + (float)(k / 3 + ho - 1);
        float px = dx + (float)(k % 3 + wo - 1);
        float y0f = floorf(py), x0f = floorf(px);
        float wy1 = py - y0f, wy0 = 1.f - wy1;
        float wx1 = px - x0f, wx0 = 1.f - wx1;
        int y0 = (int)y0f, x0i = (int)x0f;
        int y1 = y0 + 1, x1 = x0i + 1;
        bool vy0 = (y0 >= 0) && (y0 < H_), vy1 = (y1 >= 0) && (y1 < H_);
        bool vx0 = (x0i >= 0) && (x0i < W_), vx1 = (x1 >= 0) && (x1 < W_);
        float w00 = wy0 * wx0 * ((vy0 && vx0) ? m : 0.f);
        float w01 = wy0 * wx1 * ((vy0 && vx1) ? m : 0.f);
        float w10 = wy1 * wx0 * ((vy1 && vx0) ? m : 0.f);
        float w11 = wy1 * wx1 * ((vy1 && vx1) ? m : 0.f);
        int y0c = min(max(y0, 0), H_ - 1), y1c = min(max(y1, 0), H_ - 1);
        int x0c = min(max(x0i, 0), W_ - 1), x1c = min(max(x1, 0), W_ - 1);
        int i00 = y0c * W_ + x0c, i01 = y0c * W_ + x1c;
        int i10 = y1c * W_ + x0c, i11 = y1c * W_ + x1c;
#pragma unroll 1
        for (int c = 0; c < C_; ++c) {
            const float* xc = xb + c * HW_;
            float val = xc[i00] * w00 + xc[i01] * w01 + xc[i10] * w10 +
                        xc[i11] * w11;
            const float* wr = w_regp + c * 9 + k;
#pragma unroll
            for (int o = 0; o < 64; ++o)
                acc[o] = fmaf(val, wr[o * 576], acc[o]);
        }
    }
    float* ob = out + (size_t)b * O_ * HW_ + pix;
#pragma unroll
    for (int o = 0; o < 64; ++o) ob[o * HW_] = acc[o];
}

// ---------------------------------------------------------------------------
extern "C" void kernel_launch(void* const* d_in, const int* in_sizes, int n_in,
                              void* d_out, int out_size, void* d_ws,
                              size_t ws_size, hipStream_t stream) {
    const float* x     = (const float*)d_in[0];
    const float* z     = (const float*)d_in[1];
    const float* w_off = (const float*)d_in[2];
    const float* b_off = (const float*)d_in[3];
    const float* w_mod = (const float*)d_in[4];
    const float* b_mod = (const float*)d_in[5];
    const float* w_reg = (const float*)d_in[6];
    float* out = (float*)d_out;

    // ws layout (bytes): wb2 73728 | wz2 36864 | wx2 18432  -> 129024
    //                    xn 16777216 | zn 16777216
    const size_t need = 129024 + 2 * 16777216ull;

    const int npix = B_ * HW_;    // 131072
    const int nblk = npix / 128;  // 1024 blocks (2 rows x 64 cols each)

    if (ws_size >= need) {
        short* wb2 = (short*)d_ws;
        short* wz2 = wb2 + 36864;
        short* wx2 = wz2 + 18432;
        unsigned short* xn = (unsigned short*)((char*)d_ws + 129024);
        unsigned short* zn = xn + 8388608;

        prep_weights<<<144, 256, 0, stream>>>(w_off, w_mod, w_reg, wb2, wz2,
                                              wx2);
        to_nhwc<<<2048, 256, 0, stream>>>(x, z, xn, zn);
        dcn_fused<<<nblk, 512, 0, stream>>>(zn, xn, wb2, wz2, wx2, b_off,
                                            b_mod, out);
    } else {
        deform_fallback<<<(npix + 255) / 256, 256, 0, stream>>>(
            x, z, w_reg, w_off, b_off, w_mod, b_mod, out);
    }
}

// Round 18
// 121.736 us; speedup vs baseline: 1.0216x; 1.0216x over previous
//
#include <hip/hip_runtime.h>
#include <hip/hip_bf16.h>
#include <math.h>

#define B_  8
#define C_  64
#define O_  64
#define H_  128
#define W_  128
#define HW_ (H_ * W_)

typedef __attribute__((ext_vector_type(8))) short bf16x8;
typedef __attribute__((ext_vector_type(4))) float f32x4;

__device__ __forceinline__ short f2bf(float f) {
    __hip_bfloat16 h = __float2bfloat16(f);
    return *reinterpret_cast<short*>(&h);
}
__device__ __forceinline__ float bf2f(short u) {
    unsigned int v = ((unsigned int)(unsigned short)u) << 16;
    return __uint_as_float(v);
}

// Volatile asm 16B global load: forces a DISTINCT dest VGPR quad per call
// (compiler cannot sink/reuse — the R7/R8/R11/R17 allocator defeat).
// NOTE: compiler inserts NO waitcnt for asm loads — caller must s_waitcnt
// vmcnt(0) + sched_barrier(0) before consuming (guide rule 18).
__device__ __forceinline__ bf16x8 ld16g(const void* p) {
    bf16x8 r;
    asm volatile("global_load_dwordx4 %0, %1, off" : "=v"(r) : "v"(p));
    return r;
}

// ---------------------------------------------------------------------------
// Prep 1: bf16 weights, 16x16 MFMA-A layout [step][mf][l15][g][8].
//   wb2 [18][4][16][4][8]  (deform)          36864 sh
//   wz2 [18][2][16][4][8]  (offset conv)     18432 sh
//   wx2 [18][1][16][4][8]  (mask conv)        9216 sh
// ---------------------------------------------------------------------------
__global__ void prep_weights(const float* __restrict__ w_off,
                             const float* __restrict__ w_mod,
                             const float* __restrict__ w_reg,
                             short* __restrict__ wb2,
                             short* __restrict__ wz2,
                             short* __restrict__ wx2) {
    int t = blockIdx.x * blockDim.x + threadIdx.x;
    if (t < 36864) {
        int step = t / 2048, r = t % 2048;
        int mf = r / 512, r2 = r % 512;
        int l = r2 / 32, r3 = r2 % 32;
        int gg = r3 / 8, j = r3 % 8;
        int kt = step >> 1, ch = step & 1;
        int o = mf * 16 + l, c = ch * 32 + gg * 8 + j;
        wb2[t] = f2bf(w_reg[(o * 64 + c) * 9 + kt]);
    }
    if (t < 18432) {
        int step = t / 1024, r = t % 1024;
        int mf = r / 512, r2 = r % 512;
        int l = r2 / 32, r3 = r2 % 32;
        int gg = r3 / 8, j = r3 % 8;
        int kt = step >> 1, ch = step & 1;
        int m = mf * 16 + l, c = ch * 32 + gg * 8 + j;
        wz2[t] = (m < 18) ? f2bf(w_off[(m * 64 + c) * 9 + kt]) : (short)0;
    }
    if (t < 9216) {
        int step = t / 512, r = t % 512;
        int l = r / 32, r3 = r % 32;
        int gg = r3 / 8, j = r3 % 8;
        int kt = step >> 1, ch = step & 1;
        int c = ch * 32 + gg * 8 + j;
        wx2[t] = (l < 9) ? f2bf(w_mod[(l * 64 + c) * 9 + kt]) : (short)0;
    }
}

// ---------------------------------------------------------------------------
// Prep 2: NCHW fp32 -> NHWC bf16 for x and z.
// ---------------------------------------------------------------------------
__global__ __launch_bounds__(256) void to_nhwc(
    const float* __restrict__ x, const float* __restrict__ z,
    unsigned short* __restrict__ xn, unsigned short* __restrict__ zn) {
    __shared__ float t[64 * 65];
    const int bid = blockIdx.x;
    const int xseg = bid & 1;
    const int y = (bid >> 1) & 127;
    const int b = bid >> 8;

#pragma unroll
    for (int arr = 0; arr < 2; ++arr) {
        const float* src = arr ? z : x;
        unsigned short* dst = arr ? zn : xn;
#pragma unroll
        for (int i = 0; i < 16; ++i) {
            int e = threadIdx.x + i * 256;
            int c = e >> 6, px = e & 63;
            t[px * 65 + c] =
                src[((size_t)(b * 64 + c) * H_ + y) * W_ + xseg * 64 + px];
        }
        __syncthreads();
#pragma unroll
        for (int i = 0; i < 2; ++i) {
            int j = threadIdx.x + i * 256;
            int px = j >> 3, q = j & 7;
            bf16x8 v;
#pragma unroll
            for (int jj = 0; jj < 8; ++jj)
                v[jj] = f2bf(t[px * 65 + q * 8 + jj]);
            *(bf16x8*)(dst +
                       ((size_t)((b * H_ + y) * W_ + xseg * 64 + px)) * 64 +
                       q * 8) = v;
        }
        __syncthreads();
    }
}

// bilinear tap params; also returns UNCLAMPED y0,x0 for the window check
__device__ __forceinline__ void tap_params2(
    int t, int hop, int pxi, float dy, float dx, float m,
    float& w00, float& w01, float& w10, float& w11,
    int& a00, int& a01, int& a10, int& a11, int& y0u, int& x0u) {
    int ky = t / 3, kx = t - 3 * ky;
    float py = dy + (float)(ky + hop - 1);
    float pxf = dx + (float)(kx + pxi - 1);
    float y0f = floorf(py), x0f = floorf(pxf);
    float wy1 = py - y0f, wy0 = 1.f - wy1;
    float wx1 = pxf - x0f, wx0w = 1.f - wx1;
    int y0 = (int)y0f, x0i = (int)x0f;
    int y1 = y0 + 1, x1 = x0i + 1;
    bool vy0 = (y0 >= 0) && (y0 < H_), vy1 = (y1 >= 0) && (y1 < H_);
    bool vx0 = (x0i >= 0) && (x0i < W_), vx1 = (x1 >= 0) && (x1 < W_);
    w00 = wy0 * wx0w * ((vy0 && vx0) ? m : 0.f);
    w01 = wy0 * wx1 * ((vy0 && vx1) ? m : 0.f);
    w10 = wy1 * wx0w * ((vy1 && vx0) ? m : 0.f);
    w11 = wy1 * wx1 * ((vy1 && vx1) ? m : 0.f);
    int y0c = min(max(y0, 0), H_ - 1), y1c = min(max(y1, 0), H_ - 1);
    int x0c = min(max(x0i, 0), W_ - 1), x1c = min(max(x1, 0), W_ - 1);
    a00 = (y0c * W_ + x0c) * 64;
    a01 = (y0c * W_ + x1c) * 64;
    a10 = (y1c * W_ + x0c) * 64;
    a11 = (y1c * W_ + x1c) * 64;
    y0u = y0;
    x0u = x0i;
}

// ---------------------------------------------------------------------------
// FUSED conv + deform (R16 structure + R18 asm batch loads). Block = 128 px
// = 2 rows x 64 cols, 8 waves x 16 px; x window 6x69, PSTR=144B, 59.6KB LDS,
// 2 blocks/CU. Per tap: 8 asm global loads issued FIRST (distinct dest regs,
// guaranteed in-flight together), tap_params/shfl/LDS-corner work overlaps
// the latency, then vmcnt(0)+sched_barrier(0), then blend+MFMA.
// ---------------------------------------------------------------------------
#define WROW 6
#define WCOL 69
#define PSTR 72  // shorts per pixel (144B): 64 data + 8 pad -> bank-spread

__global__ __launch_bounds__(512, 4) void dcn_fused(
    const unsigned short* __restrict__ zn, const unsigned short* __restrict__ xn,
    const short* __restrict__ wb2, const short* __restrict__ wz2,
    const short* __restrict__ wx2,
    const float* __restrict__ b_off, const float* __restrict__ b_mod,
    float* __restrict__ out)
{
    __shared__ __align__(16) short sx[WROW * WCOL * PSTR];  // 59616 B

    const int tid = threadIdx.x;
    const int lane = tid & 63;
    const int wv = tid >> 6;        // 0..7
    const int l15 = lane & 15;
    const int g = lane >> 4;
    const int g8 = g * 8;

    // XCD swizzle: 1024 blocks = 8 XCDs x 128; one image per XCD L2.
    int bid = (int)blockIdx.x;
    bid = (bid & 7) * 128 + (bid >> 3);

    // 2 rows x 64 cols tile decomposition
    const int b = bid >> 7;               // 128 blocks per image
    const int rem = bid & 127;
    const int hoB = (rem >> 1) << 1;      // 0,2,..,126
    const int wxB = (rem & 1) << 6;       // 0 or 64

    const int pxi = wv * 16 + l15;        // block-relative pixel 0..127
    const int rowr = pxi >> 6;            // 0 or 1
    const int col = pxi & 63;             // 0..63
    const int hop = hoB + rowr;           // this pixel's row
    const int colg = wxB + col;           // this pixel's global column

    const unsigned short* znb = zn + (size_t)b * HW_ * 64;
    const unsigned short* xnb = xn + (size_t)b * HW_ * 64;

    // ---- stage x window: rows hoB-2..hoB+3, cols wxB-2..wxB+66 (clamped) --
    for (int t = tid; t < WROW * WCOL * 8; t += 512) {
        int pix = t >> 3, q = t & 7;
        int r = pix / WCOL, c = pix - r * WCOL;
        int gy = min(max(hoB - 2 + r, 0), H_ - 1);
        int gx = min(max(wxB - 2 + c, 0), W_ - 1);
        bf16x8 v = *(const bf16x8*)(xnb + (gy * W_ + gx) * 64 + q * 8);
        *(bf16x8*)(sx + pix * PSTR + q * 8) = v;
    }
    __syncthreads();

    // ================= Phase A: offset/mask convs =================
    f32x4 A0 = {0.f, 0.f, 0.f, 0.f}, A1 = A0, A2 = A0;
    const bf16x8 vzero = {0, 0, 0, 0, 0, 0, 0, 0};

#pragma unroll 1
    for (int kt = 0; kt < 9; ++kt) {
        const int ky = kt / 3, kx = kt - 3 * ky;
        const int iy = hop + ky - 1;
        const int ixg = colg + kx - 1;
        const bool v = (iy >= 0) && (iy < H_) && (ixg >= 0) && (ixg < W_);
        const int basez =
            (min(max(iy, 0), H_ - 1) * W_ + min(max(ixg, 0), W_ - 1)) * 64;
        const int s0 = kt * 2, s1 = s0 + 1;

        // ---- batch: 8 asm global loads (2 z chunks + 6 weight frags) ----
        bf16x8 bz0 = ld16g(znb + basez + g8);
        bf16x8 bz1 = ld16g(znb + basez + 32 + g8);
        bf16x8 az00 = ld16g(wz2 + (size_t)((s0 * 2 + 0) * 16 + l15) * 32 + g8);
        bf16x8 az01 = ld16g(wz2 + (size_t)((s0 * 2 + 1) * 16 + l15) * 32 + g8);
        bf16x8 ax0  = ld16g(wx2 + (size_t)(s0 * 16 + l15) * 32 + g8);
        bf16x8 az10 = ld16g(wz2 + (size_t)((s1 * 2 + 0) * 16 + l15) * 32 + g8);
        bf16x8 az11 = ld16g(wz2 + (size_t)((s1 * 2 + 1) * 16 + l15) * 32 + g8);
        bf16x8 ax1  = ld16g(wx2 + (size_t)(s1 * 16 + l15) * 32 + g8);

        // ---- overlap: LDS window reads for x (lgkm pipe) ----
        const short* xs = sx + ((rowr + ky + 1) * WCOL + col + kx + 1) * PSTR;
        bf16x8 bx0 = *(const bf16x8*)(xs + g8);
        bf16x8 bx1 = *(const bf16x8*)(xs + 32 + g8);

        asm volatile("s_waitcnt vmcnt(0)" ::: "memory");
        __builtin_amdgcn_sched_barrier(0);

        bz0 = v ? bz0 : vzero;
        bz1 = v ? bz1 : vzero;
        bx0 = v ? bx0 : vzero;
        bx1 = v ? bx1 : vzero;

        A0 = __builtin_amdgcn_mfma_f32_16x16x32_bf16(az00, bz0, A0, 0, 0, 0);
        A1 = __builtin_amdgcn_mfma_f32_16x16x32_bf16(az01, bz0, A1, 0, 0, 0);
        A2 = __builtin_amdgcn_mfma_f32_16x16x32_bf16(ax0, bx0, A2, 0, 0, 0);
        A0 = __builtin_amdgcn_mfma_f32_16x16x32_bf16(az10, bz1, A0, 0, 0, 0);
        A1 = __builtin_amdgcn_mfma_f32_16x16x32_bf16(az11, bz1, A1, 0, 0, 0);
        A2 = __builtin_amdgcn_mfma_f32_16x16x32_bf16(ax1, bx1, A2, 0, 0, 0);
    }

    // ================= Bridge: bias + sigmoid =================
#pragma unroll
    for (int r = 0; r < 4; ++r) A0[r] += b_off[g * 4 + r];
    if (g == 0) {
        A1[0] += b_off[16];
        A1[1] += b_off[17];
    }
    float mk0, mk1, mk2, mk3;
    {
        int j0 = g * 4;
        mk0 = 2.f / (1.f + expf(-(A2[0] + b_mod[min(j0 + 0, 8)])));
        mk1 = 2.f / (1.f + expf(-(A2[1] + b_mod[min(j0 + 1, 8)])));
        mk2 = 2.f / (1.f + expf(-(A2[2] + b_mod[min(j0 + 2, 8)])));
        mk3 = 2.f / (1.f + expf(-(A2[3] + b_mod[min(j0 + 3, 8)])));
    }
    auto get_off = [&](int t, float& dy, float& dx, float& m) {
        if (t < 8) {
            float sdy = (t & 1) ? A0[2] : A0[0];
            float sdx = (t & 1) ? A0[3] : A0[1];
            int ln = (t >> 1) * 16 + l15;
            dy = __shfl(sdy, ln, 64);
            dx = __shfl(sdx, ln, 64);
        } else {
            dy = __shfl(A1[0], l15, 64);
            dx = __shfl(A1[1], l15, 64);
        }
        int tb = t & 3;
        float sm = (tb == 0) ? mk0 : (tb == 1) ? mk1 : (tb == 2) ? mk2 : mk3;
        m = __shfl(sm, (t >> 2) * 16 + l15, 64);
    };

    // ================= Phase B: deformable conv =================
    f32x4 D0 = {0.f, 0.f, 0.f, 0.f}, D1 = D0, D2 = D0, D3 = D0;

#pragma unroll 1
    for (int kt = 0; kt < 9; ++kt) {
        const int s0 = kt * 2, s1 = s0 + 1;

        // ---- batch: 8 asm weight loads FIRST (static addrs) ----
        bf16x8 a0l = ld16g(wb2 + (size_t)((s0 * 4 + 0) * 16 + l15) * 32 + g8);
        bf16x8 a1l = ld16g(wb2 + (size_t)((s0 * 4 + 1) * 16 + l15) * 32 + g8);
        bf16x8 a2l = ld16g(wb2 + (size_t)((s0 * 4 + 2) * 16 + l15) * 32 + g8);
        bf16x8 a3l = ld16g(wb2 + (size_t)((s0 * 4 + 3) * 16 + l15) * 32 + g8);
        bf16x8 a0h = ld16g(wb2 + (size_t)((s1 * 4 + 0) * 16 + l15) * 32 + g8);
        bf16x8 a1h = ld16g(wb2 + (size_t)((s1 * 4 + 1) * 16 + l15) * 32 + g8);
        bf16x8 a2h = ld16g(wb2 + (size_t)((s1 * 4 + 2) * 16 + l15) * 32 + g8);
        bf16x8 a3h = ld16g(wb2 + (size_t)((s1 * 4 + 3) * 16 + l15) * 32 + g8);

        // ---- overlap: params + corner fetch (shfl/valu/lds pipes) ----
        float dy, dx, m;
        get_off(kt, dy, dx, m);
        float w00, w01, w10, w11;
        int a00, a01, a10, a11, y0u, x0u;
        tap_params2(kt, hop, colg, dy, dx, m, w00, w01, w10, w11, a00,
                    a01, a10, a11, y0u, x0u);

        const bool inw = (y0u >= hoB - 2) && (y0u + 1 <= hoB + 3) &&
                         (x0u >= wxB - 2) && (x0u + 1 <= wxB + 66);
        bf16x8 c0l, c1l, c2l, c3l, c0h, c1h, c2h, c3h;
        if (__all(inw)) {
            const int pix00 = (y0u - (hoB - 2)) * WCOL + (x0u - (wxB - 2));
            const short* p00 = sx + pix00 * PSTR;
            const short* p01 = p00 + PSTR;
            const short* p10 = p00 + WCOL * PSTR;
            const short* p11 = p10 + PSTR;
            c0l = *(const bf16x8*)(p00 + g8);
            c1l = *(const bf16x8*)(p01 + g8);
            c2l = *(const bf16x8*)(p10 + g8);
            c3l = *(const bf16x8*)(p11 + g8);
            c0h = *(const bf16x8*)(p00 + 32 + g8);
            c1h = *(const bf16x8*)(p01 + 32 + g8);
            c2h = *(const bf16x8*)(p10 + 32 + g8);
            c3h = *(const bf16x8*)(p11 + 32 + g8);
        } else {
            c0l = *(const bf16x8*)(xnb + a00 + g8);
            c1l = *(const bf16x8*)(xnb + a01 + g8);
            c2l = *(const bf16x8*)(xnb + a10 + g8);
            c3l = *(const bf16x8*)(xnb + a11 + g8);
            c0h = *(const bf16x8*)(xnb + a00 + 32 + g8);
            c1h = *(const bf16x8*)(xnb + a01 + 32 + g8);
            c2h = *(const bf16x8*)(xnb + a10 + 32 + g8);
            c3h = *(const bf16x8*)(xnb + a11 + 32 + g8);
        }

        asm volatile("s_waitcnt vmcnt(0)" ::: "memory");
        __builtin_amdgcn_sched_barrier(0);

#pragma unroll
        for (int ch = 0; ch < 2; ++ch) {
            bf16x8 s0v = ch ? c0h : c0l;
            bf16x8 s1v = ch ? c1h : c1l;
            bf16x8 s2v = ch ? c2h : c2l;
            bf16x8 s3v = ch ? c3h : c3l;
            bf16x8 sv;
#pragma unroll
            for (int j = 0; j < 8; ++j) {
                float s = fmaf(bf2f(s0v[j]), w00,
                          fmaf(bf2f(s1v[j]), w01,
                          fmaf(bf2f(s2v[j]), w10, bf2f(s3v[j]) * w11)));
                sv[j] = f2bf(s);
            }
            bf16x8 aa0 = ch ? a0h : a0l;
            bf16x8 aa1 = ch ? a1h : a1l;
            bf16x8 aa2 = ch ? a2h : a2l;
            bf16x8 aa3 = ch ? a3h : a3l;
            D0 = __builtin_amdgcn_mfma_f32_16x16x32_bf16(aa0, sv, D0, 0, 0, 0);
            D1 = __builtin_amdgcn_mfma_f32_16x16x32_bf16(aa1, sv, D1, 0, 0, 0);
            D2 = __builtin_amdgcn_mfma_f32_16x16x32_bf16(aa2, sv, D2, 0, 0, 0);
            D3 = __builtin_amdgcn_mfma_f32_16x16x32_bf16(aa3, sv, D3, 0, 0, 0);
        }
    }

    // epilogue: o = mf*16 + g*4 + r, pixel = (hop, colg)
    const int pixo = hop * W_ + colg;
#pragma unroll
    for (int mf = 0; mf < 4; ++mf) {
        f32x4 cc = (mf == 0) ? D0 : ((mf == 1) ? D1 : ((mf == 2) ? D2 : D3));
#pragma unroll
        for (int r = 0; r < 4; ++r) {
            const int o = mf * 16 + g * 4 + r;
            out[((size_t)b * O_ + o) * HW_ + pixo] = cc[r];
        }
    }
}

// ---------------------------------------------------------------------------
// Fallback (no workspace): fully fused fp32, slow but correct.
// ---------------------------------------------------------------------------
__global__ __launch_bounds__(256) void deform_fallback(
    const float* __restrict__ x, const float* __restrict__ z,
    const float* __restrict__ w_regp,
    const float* __restrict__ w_off, const float* __restrict__ b_off,
    const float* __restrict__ w_mod, const float* __restrict__ b_mod,
    float* __restrict__ out) {
    int p = blockIdx.x * blockDim.x + threadIdx.x;
    if (p >= B_ * HW_) return;
    int wo = p % W_;
    int ho = (p / W_) % H_;
    int b  = p / HW_;
    int pix = ho * W_ + wo;

    const float* xb = x + (size_t)b * C_ * HW_;

    float accO[18], accM[9];
#pragma unroll
    for (int j = 0; j < 18; ++j) accO[j] = b_off[j];
#pragma unroll
    for (int j = 0; j < 9; ++j) accM[j] = b_mod[j];
    const float* zb = z + (size_t)b * C_ * HW_;
#pragma unroll 1
    for (int c = 0; c < C_; ++c) {
        const float* zc = zb + c * HW_;
        const float* xc = xb + c * HW_;
#pragma unroll
        for (int ky = 0; ky < 3; ++ky) {
            int iy = ho + ky - 1;
            bool vy = (iy >= 0) && (iy < H_);
#pragma unroll
            for (int kx = 0; kx < 3; ++kx) {
                int ix = wo + kx - 1;
                bool v = vy && (ix >= 0) && (ix < W_);
                int k = ky * 3 + kx;
                float zv = v ? zc[iy * W_ + ix] : 0.f;
                float xv = v ? xc[iy * W_ + ix] : 0.f;
#pragma unroll
                for (int j = 0; j < 18; ++j)
                    accO[j] = fmaf(zv, w_off[j * 576 + c * 9 + k], accO[j]);
#pragma unroll
                for (int j = 0; j < 9; ++j)
                    accM[j] = fmaf(xv, w_mod[j * 576 + c * 9 + k], accM[j]);
            }
        }
    }
    float mv[9];
#pragma unroll
    for (int j = 0; j < 9; ++j) mv[j] = 2.f / (1.f + expf(-accM[j]));

    float acc[64];
#pragma unroll
    for (int o = 0; o < 64; ++o) acc[o] = 0.f;

#pragma unroll 1
    for (int k = 0; k < 9; ++k) {
        float dy = accO[2 * k], dx = accO[2 * k + 1], m = mv[k];
        float py = dy + (float)(k / 3 + ho - 1);
        float px = dx + (float)(k % 3 + wo - 1);
        float y0f = floorf(py), x0f = floorf(px);
        float wy1 = py - y0f, wy0 = 1.f - wy1;
        float wx1 = px - x0f, wx0 = 1.f - wx1;
        int y0 = (int)y0f, x0i = (int)x0f;
        int y1 = y0 + 1, x1 = x0i + 1;
        bool vy0 = (y0 >= 0) && (y0 < H_), vy1 = (y1 >= 0) && (y1 < H_);
        bool vx0 = (x0i >= 0) && (x0i < W_), vx1 = (x1 >= 0) && (x1 < W_);
        float w00 = wy0 * wx0 * ((vy0 && vx0) ? m : 0.f);
        float w01 = wy0 * wx1 * ((vy0 && vx1) ? m : 0.f);
        float w10 = wy1 * wx0 * ((vy1 && vx0) ? m : 0.f);
        float w11 = wy1 * wx1 * ((vy1 && vx1) ? m : 0.f);
        int y0c = min(max(y0, 0), H_ - 1), y1c = min(max(y1, 0), H_ - 1);
        int x0c = min(max(x0i, 0), W_ - 1), x1c = min(max(x1, 0), W_ - 1);
        int i00 = y0c * W_ + x0c, i01 = y0c * W_ + x1c;
        int i10 = y1c * W_ + x0c, i11 = y1c * W_ + x1c;
#pragma unroll 1
        for (int c = 0; c < C_; ++c) {
            const float* xc = xb + c * HW_;
            float val = xc[i00] * w00 + xc[i01] * w01 + xc[i10] * w10 +
                        xc[i11] * w11;
            const float* wr = w_regp + c * 9 + k;
#pragma unroll
            for (int o = 0; o < 64; ++o)
                acc[o] = fmaf(val, wr[o * 576], acc[o]);
        }
    }
    float* ob = out + (size_t)b * O_ * HW_ + pix;
#pragma unroll
    for (int o = 0; o < 64; ++o) ob[o * HW_] = acc[o];
}

// ---------------------------------------------------------------------------
extern "C" void kernel_launch(void* const* d_in, const int* in_sizes, int n_in,
                              void* d_out, int out_size, void* d_ws,
                              size_t ws_size, hipStream_t stream) {
    const float* x     = (const float*)d_in[0];
    const float* z     = (const float*)d_in[1];
    const float* w_off = (const float*)d_in[2];
    const float* b_off = (const float*)d_in[3];
    const float* w_mod = (const float*)d_in[4];
    const float* b_mod = (const float*)d_in[5];
    const float* w_reg = (const float*)d_in[6];
    float* out = (float*)d_out;

    // ws layout (bytes): wb2 73728 | wz2 36864 | wx2 18432  -> 129024
    //                    xn 16777216 | zn 16777216
    const size_t need = 129024 + 2 * 16777216ull;

    const int npix = B_ * HW_;    // 131072
    const int nblk = npix / 128;  // 1024 blocks (2 rows x 64 cols each)

    if (ws_size >= need) {
        short* wb2 = (short*)d_ws;
        short* wz2 = wb2 + 36864;
        short* wx2 = wz2 + 18432;
        unsigned short* xn = (unsigned short*)((char*)d_ws + 129024);
        unsigned short* zn = xn + 8388608;

        prep_weights<<<144, 256, 0, stream>>>(w_off, w_mod, w_reg, wb2, wz2,
                                              wx2);
        to_nhwc<<<2048, 256, 0, stream>>>(x, z, xn, zn);
        dcn_fused<<<nblk, 512, 0, stream>>>(zn, xn, wb2, wz2, wx2, b_off,
                                            b_mod, out);
    } else {
        deform_fallback<<<(npix + 255) / 256, 256, 0, stream>>>(
            x, z, w_reg, w_off, b_off, w_mod, b_mod, out);
    }
}